// Round 8
// baseline (42736.029 us; speedup 1.0000x reference)
//
#include <hip/hip_runtime.h>
#include <math.h>

#define HH 512
#define EE 256
#define BB 64
#define TT 64
#define VV 32000
#define H3 1536
#define TDEC 63

__device__ __forceinline__ float sigm(float x) { return 1.f / (1.f + expf(-x)); }

// ---------------- device-wide barrier (agent scope), centralized generation counter
__device__ __forceinline__ void gbar(unsigned* cnt, unsigned* gen, unsigned nblk) {
    __syncthreads();
    if (threadIdx.x == 0) {
        __threadfence();   // make this block's writes visible device-wide
        unsigned g = __hip_atomic_load(gen, __ATOMIC_RELAXED, __HIP_MEMORY_SCOPE_AGENT);
        unsigned a = __hip_atomic_fetch_add(cnt, 1u, __ATOMIC_ACQ_REL, __HIP_MEMORY_SCOPE_AGENT);
        if (a == nblk - 1u) {
            __hip_atomic_store(cnt, 0u, __ATOMIC_RELAXED, __HIP_MEMORY_SCOPE_AGENT);
            __hip_atomic_fetch_add(gen, 1u, __ATOMIC_ACQ_REL, __HIP_MEMORY_SCOPE_AGENT);
        } else {
            while (__hip_atomic_load(gen, __ATOMIC_ACQUIRE, __HIP_MEMORY_SCOPE_AGENT) == g)
                __builtin_amdgcn_s_sleep(1);
        }
        __threadfence();
    }
    __syncthreads();
}

__global__ void k_bar_init(unsigned* bar) { bar[0] = 0u; bar[1] = 0u; }

// ---------------- embedding gather: x[b*T+t][e] = emb[src[b*T+t]][e]
__global__ void k_embed(const int* __restrict__ src, const float* __restrict__ emb,
                        float* __restrict__ x) {
    int idx = blockIdx.x * 256 + threadIdx.x;      // B*T*E = 1048576
    int row = idx >> 8;
    int e = idx & 255;
    x[idx] = emb[src[row] * EE + e];
}

// ---------------- 128x128 fp32 GEMM + bias, 8x8 micro-tile (split 64+64), R5-proven
__global__ __launch_bounds__(256) void k_gemm128_bias(
    const float* __restrict__ A, const float* __restrict__ W,
    const float* __restrict__ bias, float* __restrict__ C,
    int N, int K) {
    __shared__ float As[8][128];
    __shared__ float Bs[8][128];
    int row0 = blockIdx.y * 128, col0 = blockIdx.x * 128;
    int tid = threadIdx.x;
    int tx = tid & 15, ty = tid >> 4;
    int ar = tid >> 1, aq = tid & 1;
    int bkk = tid >> 5, bc4 = tid & 31;
    float acc[2][2][4][4] = {};
    for (int k0 = 0; k0 < K; k0 += 8) {
        float4 av = *(const float4*)&A[(size_t)(row0 + ar) * K + k0 + aq * 4];
        float4 bv = *(const float4*)&W[(size_t)(k0 + bkk) * N + col0 + bc4 * 4];
        As[aq * 4 + 0][ar] = av.x;
        As[aq * 4 + 1][ar] = av.y;
        As[aq * 4 + 2][ar] = av.z;
        As[aq * 4 + 3][ar] = av.w;
        *(float4*)&Bs[bkk][bc4 * 4] = bv;
        __syncthreads();
#pragma unroll
        for (int kk = 0; kk < 8; ++kk) {
            float4 a0 = *(const float4*)&As[kk][ty * 4];
            float4 a1 = *(const float4*)&As[kk][64 + ty * 4];
            float4 b0 = *(const float4*)&Bs[kk][tx * 4];
            float4 b1 = *(const float4*)&Bs[kk][64 + tx * 4];
            float a_[2][4] = {{a0.x, a0.y, a0.z, a0.w}, {a1.x, a1.y, a1.z, a1.w}};
            float b_[2][4] = {{b0.x, b0.y, b0.z, b0.w}, {b1.x, b1.y, b1.z, b1.w}};
#pragma unroll
            for (int rh = 0; rh < 2; ++rh)
#pragma unroll
                for (int i = 0; i < 4; ++i)
#pragma unroll
                    for (int ch = 0; ch < 2; ++ch)
#pragma unroll
                        for (int j = 0; j < 4; ++j)
                            acc[rh][ch][i][j] = fmaf(a_[rh][i], b_[ch][j], acc[rh][ch][i][j]);
        }
        __syncthreads();
    }
#pragma unroll
    for (int rh = 0; rh < 2; ++rh)
#pragma unroll
        for (int i = 0; i < 4; ++i) {
            int row = row0 + rh * 64 + ty * 4 + i;
#pragma unroll
            for (int ch = 0; ch < 2; ++ch) {
                int c = col0 + ch * 64 + tx * 4;
                float4 bv = *(const float4*)&bias[c];
                float4 o;
                o.x = acc[rh][ch][i][0] + bv.x;
                o.y = acc[rh][ch][i][1] + bv.y;
                o.z = acc[rh][ch][i][2] + bv.z;
                o.w = acc[rh][ch][i][3] + bv.w;
                *(float4*)&C[(size_t)row * N + c] = o;
            }
        }
}

// ---------------- persistent GRU layer: R7's k_gru5 body per step + gbar (no per-step launch)
// grid: nblk per direction (256 = 16bg x 16ic), f||b uses 512 total.
struct GruL {
    const float* xg;     // (B*T, 3H)
    float* y;            // carried h / output
    const float* U;      // (H, 3H)
    const float* b1;     // (3H)
    int ystride, yoff, rev;
};

__global__ __launch_bounds__(512) void k_gru_persist(
    GruL pa, GruL pb, const int* __restrict__ src, int nblk, int totblk,
    unsigned* cnt, unsigned* gen) {
    GruL p = ((int)blockIdx.x < nblk) ? pa : pb;
    int blk = ((int)blockIdx.x < nblk) ? blockIdx.x : blockIdx.x - nblk;
    int bg = blk >> 4;                 // batches bg*4 .. bg*4+3
    int ic = blk & 15;                 // 32-col chunk
    int tid = threadIdx.x;
    int c = tid & 31, kh = tid >> 5;   // kh 0..15, each owns 32 k
    int i = ic * 32 + c;
    __shared__ float hs[4][512];
    __shared__ float ps[12][512];
    for (int s = 0; s < TT; ++s) {
        int t = p.rev ? (63 - s) : s;
        int tprev = p.rev ? (t + 1) : (t - 1);
        for (int j = tid; j < 2048; j += 512) {
            int bl = j >> 9, k = j & 511;
            hs[bl][k] = (s == 0) ? 0.f
                : p.y[(size_t)((bg * 4 + bl) * TT + tprev) * p.ystride + p.yoff + k];
        }
        __syncthreads();
        float az[4] = {}, ar[4] = {}, ah[4] = {};
        const float* Up = p.U + (size_t)(kh * 32) * H3 + i;
        int ks0 = kh * 32;
#pragma unroll 8
        for (int k = 0; k < 32; ++k) {
            const float* Ur = Up + k * H3;
            float uz = Ur[0], ur = Ur[512], uh = Ur[1024];
#pragma unroll
            for (int b = 0; b < 4; ++b) {
                float h = hs[b][ks0 + k];
                az[b] = fmaf(h, uz, az[b]);
                ar[b] = fmaf(h, ur, ar[b]);
                ah[b] = fmaf(h, uh, ah[b]);
            }
        }
#pragma unroll
        for (int b = 0; b < 4; ++b) {
            ps[b][tid] = az[b];
            ps[4 + b][tid] = ar[b];
            ps[8 + b][tid] = ah[b];
        }
        __syncthreads();
        if (tid < 128) {
            int b = tid >> 5, cc = tid & 31;
            float AZ = 0.f, AR = 0.f, AH = 0.f;
            for (int q = 0; q < 16; ++q) {
                AZ += ps[b][q * 32 + cc];
                AR += ps[4 + b][q * 32 + cc];
                AH += ps[8 + b][q * 32 + cc];
            }
            int ii = ic * 32 + cc;
            int row = (bg * 4 + b) * TT + t;
            const float* xr = p.xg + (size_t)row * H3;
            float z = sigm(xr[ii] + AZ + p.b1[ii]);
            float r = sigm(xr[512 + ii] + AR + p.b1[512 + ii]);
            float hc = sigm(xr[1024 + ii] + r * (AH + p.b1[1024 + ii]));
            float hp = hs[b][ii];
            float hn = (src[row] != 0) ? (z * hp + (1.f - z) * hc) : hp;
            p.y[(size_t)row * p.ystride + p.yoff + ii] = hn;
        }
        gbar(cnt, gen, (unsigned)totblk);
    }
}

// ---------------- decoder init: h0[b][i] = enc[b][T-1][i]
__global__ void k_copy_h0(const float* __restrict__ enc, float* __restrict__ h0) {
    int idx = blockIdx.x * 256 + threadIdx.x;
    int b = idx >> 9, i = idx & 511;
    h0[idx] = enc[((size_t)(b * TT + (TT - 1))) * HH + i];
}

// ---------------- persistent decoder: 63 steps x {qgemm, attn, dec_gru5} + 3 gbar/step
// grid 256 x 512. Phase bodies = proven R7 kernels.
__global__ __launch_bounds__(512) void k_decoder_p(
    const float* KEYS, const float* ENC, const float* H0v, float* HMAT,
    const float* aW2, const float* ab2, const float* aV, const float* abV,
    const float* emb_en, const int* trg, const float* Wd, const float* bd,
    float* Qv, float* XIN, unsigned* cnt, unsigned* gen) {
    int blk = blockIdx.x;
    int tid = threadIdx.x;
    __shared__ float xs[4][768];       // phase C staging; xs[0] doubles as h/q scratch
    __shared__ float ps[12][512];
    __shared__ float sc[TT];
    float* q1 = &xs[0][0];
    for (int t = 0; t < TDEC; ++t) {
        const float* hb = t ? (HMAT + (size_t)(t - 1) * (BB * HH)) : H0v;
        // ---- phase A: q = h @ aW2 + ab2 (k_qgemm body; 64 b x 4 col-chunks)
        {
            int b = blk >> 2, coff = (blk & 3) << 7;
            int il = tid & 127, kh = tid >> 7, cq = coff + il;
            q1[tid] = hb[b * HH + tid];
            __syncthreads();
            float acc = 0.f;
            const float* Wp = aW2 + (size_t)(kh * 128) * HH + cq;
            const float* hk = q1 + kh * 128;
#pragma unroll 8
            for (int k = 0; k < 128; ++k) acc = fmaf(hk[k], Wp[k * HH], acc);
            if (kh) ps[0][(kh - 1) * 128 + il] = acc;
            __syncthreads();
            if (kh == 0)
                Qv[b * HH + cq] = acc + ps[0][il] + ps[0][128 + il] + ps[0][256 + il] + ab2[cq];
        }
        gbar(cnt, gen, 256u);
        // ---- phase B: attention + context + xin (blocks 0..63 active)
        {
            int b = blk;
            bool act = (blk < 64);
            if (act) q1[tid] = Qv[b * HH + tid];
            __syncthreads();
            if (act && tid < 256) {
                int s = tid >> 2, part = tid & 3;
                float pp = 0.f;
                const float* kr = KEYS + (size_t)(b * TT + s) * HH;
                for (int h = part * 128; h < part * 128 + 128; ++h)
                    pp += tanhf(kr[h] + q1[h]) * aV[h];
                pp += __shfl_down(pp, 1);
                pp += __shfl_down(pp, 2);
                if (part == 0) sc[s] = pp + abV[0];
            }
            __syncthreads();
            if (tid < 64) {
                float v = act ? sc[tid] : 0.f;
                float m = v;
                for (int o = 1; o < 64; o <<= 1) m = fmaxf(m, __shfl_xor(m, o));
                float e = expf(v - m);
                float su = e;
                for (int o = 1; o < 64; o <<= 1) su += __shfl_xor(su, o);
                if (act) sc[tid] = e / su;
            }
            __syncthreads();
            if (act) {
                int h = tid;             // 512 threads, one h each (same per-h sum order)
                float cx = 0.f;
                for (int ss = 0; ss < TT; ++ss)
                    cx += sc[ss] * ENC[(size_t)(b * TT + ss) * HH + h];
                XIN[b * 768 + h] = cx;
                if (tid < 256) {
                    int tok = (t == 0) ? 1 : trg[b * TT + t];
                    XIN[b * 768 + 512 + tid] = emb_en[tok * EE + tid];
                }
            }
        }
        gbar(cnt, gen, 256u);
        // ---- phase C: decoder GRU (k_dec_gru5 body; 16 bg x 16 ic)
        {
            int bg = blk >> 4, ic = blk & 15;
            int c = tid & 31, kh = tid >> 5;
            int i = ic * 32 + c;
            for (int j = tid; j < 4 * 768; j += 512) {
                int bl = j / 768, k = j - bl * 768;
                xs[bl][k] = XIN[(bg * 4 + bl) * 768 + k];
            }
            __syncthreads();
            float az[4] = {}, ar[4] = {}, ah[4] = {};
            const float* Wp = Wd + (size_t)(kh * 48) * H3 + i;
            int ks0 = kh * 48;
#pragma unroll 8
            for (int k = 0; k < 48; ++k) {
                const float* Wr = Wp + k * H3;
                float wz = Wr[0], wr = Wr[512], wh = Wr[1024];
#pragma unroll
                for (int b = 0; b < 4; ++b) {
                    float x = xs[b][ks0 + k];
                    az[b] = fmaf(x, wz, az[b]);
                    ar[b] = fmaf(x, wr, ar[b]);
                    ah[b] = fmaf(x, wh, ah[b]);
                }
            }
#pragma unroll
            for (int b = 0; b < 4; ++b) {
                ps[b][tid] = az[b];
                ps[4 + b][tid] = ar[b];
                ps[8 + b][tid] = ah[b];
            }
            __syncthreads();
            if (tid < 128) {
                int b = tid >> 5, cc = tid & 31;
                float AZ = 0.f, AR = 0.f, AH = 0.f;
                for (int q = 0; q < 16; ++q) {
                    AZ += ps[b][q * 32 + cc];
                    AR += ps[4 + b][q * 32 + cc];
                    AH += ps[8 + b][q * 32 + cc];
                }
                int ii = ic * 32 + cc;
                const float* b0 = bd;
                const float* b1 = bd + H3;
                float z = sigm(AZ + b0[ii] + b1[ii]);
                float r = sigm(AR + b0[512 + ii] + b1[512 + ii]);
                float hc = sigm(AH + b0[1024 + ii] + r * b1[1024 + ii]);
                HMAT[((size_t)t * BB + bg * 4 + b) * HH + ii] = (1.f - z) * hc;
            }
        }
        gbar(cnt, gen, 256u);
    }
}

// ---------------- logits GEMM (128x128, 8x8 micro) with fused online-LSE partials
__global__ __launch_bounds__(256) void k_gemm128_ce(
    const float* __restrict__ A, const float* __restrict__ W,
    const float* __restrict__ bias, const int* __restrict__ trg,
    float* __restrict__ pmax, float* __restrict__ psum, float* __restrict__ tgtl) {
    __shared__ float As[8][128];
    __shared__ float Bs[8][128];
    __shared__ float pm[128][17];
    __shared__ float ps[128][17];
    int row0 = blockIdx.y * 128, col0 = blockIdx.x * 128;
    int tid = threadIdx.x;
    int tx = tid & 15, ty = tid >> 4;
    int ar = tid >> 1, aq = tid & 1;
    int bkk = tid >> 5, bc4 = tid & 31;
    int arow = row0 + ar;
    if (arow > 4031) arow = 4031;   // clamp pad rows (reads stay in HMAT)
    float acc[2][2][4][4] = {};
    for (int k0 = 0; k0 < 512; k0 += 8) {
        float4 av = *(const float4*)&A[(size_t)arow * 512 + k0 + aq * 4];
        float4 bv = *(const float4*)&W[(size_t)(k0 + bkk) * VV + col0 + bc4 * 4];
        As[aq * 4 + 0][ar] = av.x;
        As[aq * 4 + 1][ar] = av.y;
        As[aq * 4 + 2][ar] = av.z;
        As[aq * 4 + 3][ar] = av.w;
        *(float4*)&Bs[bkk][bc4 * 4] = bv;
        __syncthreads();
#pragma unroll
        for (int kk = 0; kk < 8; ++kk) {
            float4 a0 = *(const float4*)&As[kk][ty * 4];
            float4 a1 = *(const float4*)&As[kk][64 + ty * 4];
            float4 b0 = *(const float4*)&Bs[kk][tx * 4];
            float4 b1 = *(const float4*)&Bs[kk][64 + tx * 4];
            float a_[2][4] = {{a0.x, a0.y, a0.z, a0.w}, {a1.x, a1.y, a1.z, a1.w}};
            float b_[2][4] = {{b0.x, b0.y, b0.z, b0.w}, {b1.x, b1.y, b1.z, b1.w}};
#pragma unroll
            for (int rh = 0; rh < 2; ++rh)
#pragma unroll
                for (int i = 0; i < 4; ++i)
#pragma unroll
                    for (int ch = 0; ch < 2; ++ch)
#pragma unroll
                        for (int j = 0; j < 4; ++j)
                            acc[rh][ch][i][j] = fmaf(a_[rh][i], b_[ch][j], acc[rh][ch][i][j]);
        }
        __syncthreads();
    }
#pragma unroll
    for (int rh = 0; rh < 2; ++rh)
#pragma unroll
        for (int i = 0; i < 4; ++i) {
            int rl = rh * 64 + ty * 4 + i;
            int rg = row0 + rl;
            int tdec = rg >> 6, bq = rg & 63;
            int tgt = (rg < 4032) ? trg[bq * TT + tdec + 1] : -1;
            float vv[8];
            float lm = -1e30f;
#pragma unroll
            for (int ch = 0; ch < 2; ++ch)
#pragma unroll
                for (int j = 0; j < 4; ++j) {
                    int c = col0 + ch * 64 + tx * 4 + j;
                    float v = acc[rh][ch][i][j] + bias[c];
                    vv[ch * 4 + j] = v;
                    lm = fmaxf(lm, v);
                    if (c == tgt) tgtl[rg] = v;
                }
            float ls = 0.f;
#pragma unroll
            for (int q = 0; q < 8; ++q) ls += expf(vv[q] - lm);
            pm[rl][tx] = lm;
            ps[rl][tx] = ls;
        }
    __syncthreads();
    if (tid < 128) {
        float M = -1e30f, S = 0.f;
        for (int x = 0; x < 16; ++x) {
            float m_ = pm[tid][x], s_ = ps[tid][x];
            if (m_ > M) { S = S * expf(M - m_) + s_; M = m_; }
            else        { S += s_ * expf(m_ - M); }
        }
        int rg = row0 + tid;
        if (rg < 4032) {
            pmax[(size_t)blockIdx.x * 4032 + rg] = M;
            psum[(size_t)blockIdx.x * 4032 + rg] = S;
        }
    }
}

// ---------------- merge partials per row -> per-block (ce_sum, valid_sum); coalesced
__global__ void k_merge(const float* __restrict__ pmax, const float* __restrict__ psum,
                        const float* __restrict__ tgtl, const int* __restrict__ trg,
                        float* __restrict__ blk) {
    int row = blockIdx.x * 64 + threadIdx.x;  // 4032 rows
    float M = -1e30f, S = 0.f;
    for (int c = 0; c < 250; ++c) {
        float m = pmax[(size_t)c * 4032 + row], s = psum[(size_t)c * 4032 + row];
        if (m > M) { S = S * expf(M - m) + s; M = m; }
        else       { S += s * expf(m - M); }
    }
    float lse = M + logf(S);
    int tdec = row >> 6, b = row & 63;
    int tgt = trg[b * TT + tdec + 1];
    float valid = (tgt != 0) ? 1.f : 0.f;
    float ce = (lse - tgtl[row]) * valid;
    float vs = valid;
    for (int o = 32; o > 0; o >>= 1) {
        ce += __shfl_down(ce, o);
        vs += __shfl_down(vs, o);
    }
    if (threadIdx.x == 0) {
        blk[blockIdx.x * 2] = ce;
        blk[blockIdx.x * 2 + 1] = vs;
    }
}

__global__ void k_final(const float* __restrict__ blk, float* __restrict__ out) {
    float s0 = 0.f, s1 = 0.f;
    for (int i = 0; i < 63; ++i) { s0 += blk[2 * i]; s1 += blk[2 * i + 1]; }
    out[0] = s0 / s1;
}

extern "C" void kernel_launch(void* const* d_in, const int* in_sizes, int n_in,
                              void* d_out, int out_size, void* d_ws, size_t ws_size,
                              hipStream_t stream) {
    const int* src = (const int*)d_in[0];
    const int* trg = (const int*)d_in[1];
    const float* emb_cn = (const float*)d_in[2];
    const float* Wf = (const float*)d_in[3];
    const float* Uf = (const float*)d_in[4];
    const float* bf = (const float*)d_in[5];
    const float* Wb = (const float*)d_in[6];
    const float* Ub = (const float*)d_in[7];
    const float* bb = (const float*)d_in[8];
    const float* Wm = (const float*)d_in[9];
    const float* Um = (const float*)d_in[10];
    const float* bm = (const float*)d_in[11];
    const float* Wt = (const float*)d_in[12];
    const float* Ut = (const float*)d_in[13];
    const float* bt = (const float*)d_in[14];
    const float* emb_en = (const float*)d_in[15];
    const float* aW1 = (const float*)d_in[16];
    const float* ab1 = (const float*)d_in[17];
    const float* aW2 = (const float*)d_in[18];
    const float* ab2 = (const float*)d_in[19];
    const float* aV = (const float*)d_in[20];
    const float* abV = (const float*)d_in[21];
    const float* Wd = (const float*)d_in[22];
    const float* bd = (const float*)d_in[24];
    const float* fcW = (const float*)d_in[25];
    const float* fcb = (const float*)d_in[26];
    float* ws = (float*)d_ws;
    float* out = (float*)d_out;

    // workspace layout (floats); PMAX/PSUM alias the x_emb/XG region (dead by then)
    float* X_EMB = ws;                    // 1,048,576
    float* XG    = ws + 1048576;          // 6,291,456
    float* PMAX  = ws;                    // 1,008,000 (alias, 250 x 4032)
    float* PSUM  = ws + 1008000;          // 1,008,000 (alias)
    float* X2    = ws + 7340032;          // 4,194,304
    float* XGB   = ws + 11534336;         // 6,291,456 (aliases Y3/ENC/KEYS, dead during f||b)
    float* Y3    = ws + 11534336;         // 2,097,152
    float* ENC   = ws + 13631488;         // 2,097,152
    float* KEYS  = ws + 15728640;         // 2,097,152
    float* HMAT  = ws + 17825792;         // 2,064,384
    float* H0v   = ws + 19890176;         // 32,768
    float* Qv    = ws + 19922944;         // 32,768
    float* XIN   = ws + 19955712;         // 49,152
    float* TGTL  = ws + 20004864;         // 4,032
    float* BLK   = ws + 20008896;         // 126
    // barrier lives in X_EMB tail: dead after f/b gemms, clear of PMAX(<1,008,000),
    // inside PSUM which is only written after the decoder finishes.
    unsigned* BAR = (unsigned*)(ws + 1048000);

    k_embed<<<4096, 256, 0, stream>>>(src, emb_cn, X_EMB);

    // x-gates for f and b (independent)
    k_gemm128_bias<<<dim3(12, 32), 256, 0, stream>>>(X_EMB, Wf, bf, XG, 1536, 256);
    k_gemm128_bias<<<dim3(12, 32), 256, 0, stream>>>(X_EMB, Wb, bb, XGB, 1536, 256);
    k_bar_init<<<1, 1, 0, stream>>>(BAR);

    // f||b persistent layer (512 blocks = 256 fwd + 256 bwd, 64 steps, 1 gbar/step)
    {
        GruL pa{XG, X2, Uf, bf + H3, 1024, 0, 0};
        GruL pb{XGB, X2, Ub, bb + H3, 1024, 512, 1};
        int nblk = 256, totblk = 512;
        unsigned* cnt = BAR; unsigned* gen = BAR + 1;
        void* args[] = {&pa, &pb, (void*)&src, &nblk, &totblk, &cnt, &gen};
        hipLaunchCooperativeKernel((void*)k_gru_persist, dim3(512), dim3(512), args, 0, stream);
    }
    // layer m
    k_gemm128_bias<<<dim3(12, 32), 256, 0, stream>>>(X2, Wm, bm, XG, 1536, 1024);
    {
        GruL pa{XG, Y3, Um, bm + H3, 512, 0, 0};
        int nblk = 256, totblk = 256;
        unsigned* cnt = BAR; unsigned* gen = BAR + 1;
        void* args[] = {&pa, &pa, (void*)&src, &nblk, &totblk, &cnt, &gen};
        hipLaunchCooperativeKernel((void*)k_gru_persist, dim3(256), dim3(512), args, 0, stream);
    }
    // layer t
    k_gemm128_bias<<<dim3(12, 32), 256, 0, stream>>>(Y3, Wt, bt, XG, 1536, 512);
    {
        GruL pa{XG, ENC, Ut, bt + H3, 512, 0, 0};
        int nblk = 256, totblk = 256;
        unsigned* cnt = BAR; unsigned* gen = BAR + 1;
        void* args[] = {&pa, &pa, (void*)&src, &nblk, &totblk, &cnt, &gen};
        hipLaunchCooperativeKernel((void*)k_gru_persist, dim3(256), dim3(512), args, 0, stream);
    }
    // keys + decoder init
    k_gemm128_bias<<<dim3(4, 32), 256, 0, stream>>>(ENC, aW1, ab1, KEYS, 512, 512);
    k_copy_h0<<<128, 256, 0, stream>>>(ENC, H0v);

    // persistent decoder: 63 steps x 3 phases, 3 gbar/step
    {
        const float* keysp = KEYS; const float* encp = ENC; const float* h0p = H0v;
        float* hmatp = HMAT; float* qvp = Qv; float* xinp = XIN;
        unsigned* cnt = BAR; unsigned* gen = BAR + 1;
        void* args[] = {(void*)&keysp, (void*)&encp, (void*)&h0p, &hmatp,
                        (void*)&aW2, (void*)&ab2, (void*)&aV, (void*)&abV,
                        (void*)&emb_en, (void*)&trg, (void*)&Wd, (void*)&bd,
                        &qvp, &xinp, &cnt, &gen};
        hipLaunchCooperativeKernel((void*)k_decoder_p, dim3(256), dim3(512), args, 0, stream);
    }

    // batched logits + CE
    k_gemm128_ce<<<dim3(250, 32), 256, 0, stream>>>(HMAT, fcW, fcb, trg, PMAX, PSUM, TGTL);
    k_merge<<<63, 64, 0, stream>>>(PMAX, PSUM, TGTL, trg, BLK);
    k_final<<<1, 1, 0, stream>>>(BLK, out);
}

// Round 9
// 7499.616 us; speedup vs baseline: 5.6984x; 5.6984x over previous
//
#include <hip/hip_runtime.h>
#include <math.h>

#define HH 512
#define EE 256
#define BB 64
#define TT 64
#define VV 32000
#define H3 1536
#define TDEC 63

__device__ __forceinline__ float sigm(float x) { return 1.f / (1.f + expf(-x)); }

// ---------------- embedding gather: x[b*T+t][e] = emb[src[b*T+t]][e]
__global__ void k_embed(const int* __restrict__ src, const float* __restrict__ emb,
                        float* __restrict__ x) {
    int idx = blockIdx.x * 256 + threadIdx.x;      // B*T*E = 1048576
    int row = idx >> 8;
    int e = idx & 255;
    x[idx] = emb[src[row] * EE + e];
}

// ---------------- 128x128 fp32 GEMM + bias, 8x8 micro-tile (split 64+64), R5-proven
__global__ __launch_bounds__(256) void k_gemm128_bias(
    const float* __restrict__ A, const float* __restrict__ W,
    const float* __restrict__ bias, float* __restrict__ C,
    int N, int K) {
    __shared__ float As[8][128];
    __shared__ float Bs[8][128];
    int row0 = blockIdx.y * 128, col0 = blockIdx.x * 128;
    int tid = threadIdx.x;
    int tx = tid & 15, ty = tid >> 4;
    int ar = tid >> 1, aq = tid & 1;
    int bkk = tid >> 5, bc4 = tid & 31;
    float acc[2][2][4][4] = {};
    for (int k0 = 0; k0 < K; k0 += 8) {
        float4 av = *(const float4*)&A[(size_t)(row0 + ar) * K + k0 + aq * 4];
        float4 bv = *(const float4*)&W[(size_t)(k0 + bkk) * N + col0 + bc4 * 4];
        As[aq * 4 + 0][ar] = av.x;
        As[aq * 4 + 1][ar] = av.y;
        As[aq * 4 + 2][ar] = av.z;
        As[aq * 4 + 3][ar] = av.w;
        *(float4*)&Bs[bkk][bc4 * 4] = bv;
        __syncthreads();
#pragma unroll
        for (int kk = 0; kk < 8; ++kk) {
            float4 a0 = *(const float4*)&As[kk][ty * 4];
            float4 a1 = *(const float4*)&As[kk][64 + ty * 4];
            float4 b0 = *(const float4*)&Bs[kk][tx * 4];
            float4 b1 = *(const float4*)&Bs[kk][64 + tx * 4];
            float a_[2][4] = {{a0.x, a0.y, a0.z, a0.w}, {a1.x, a1.y, a1.z, a1.w}};
            float b_[2][4] = {{b0.x, b0.y, b0.z, b0.w}, {b1.x, b1.y, b1.z, b1.w}};
#pragma unroll
            for (int rh = 0; rh < 2; ++rh)
#pragma unroll
                for (int i = 0; i < 4; ++i)
#pragma unroll
                    for (int ch = 0; ch < 2; ++ch)
#pragma unroll
                        for (int j = 0; j < 4; ++j)
                            acc[rh][ch][i][j] = fmaf(a_[rh][i], b_[ch][j], acc[rh][ch][i][j]);
        }
        __syncthreads();
    }
#pragma unroll
    for (int rh = 0; rh < 2; ++rh)
#pragma unroll
        for (int i = 0; i < 4; ++i) {
            int row = row0 + rh * 64 + ty * 4 + i;
#pragma unroll
            for (int ch = 0; ch < 2; ++ch) {
                int c = col0 + ch * 64 + tx * 4;
                float4 bv = *(const float4*)&bias[c];
                float4 o;
                o.x = acc[rh][ch][i][0] + bv.x;
                o.y = acc[rh][ch][i][1] + bv.y;
                o.z = acc[rh][ch][i][2] + bv.z;
                o.w = acc[rh][ch][i][3] + bv.w;
                *(float4*)&C[(size_t)row * N + c] = o;
            }
        }
}

// ---------------- GRU recurrent step, 4-batch-shared / 256-block / split-k-16 (R7-proven)
struct GruP {
    const float* xg;     // (B*T, 3H)
    const float* hb;     // carried h base (nullptr -> zeros)
    float* y;
    const float* U;      // (H, 3H)
    const float* b1;     // (3H)
    int t, tprev, ystride, yoff;
};

__global__ __launch_bounds__(512) void k_gru5(GruP p0, GruP p1, const int* __restrict__ src,
                                              int nblk) {
    GruP p = (blockIdx.x < nblk) ? p0 : p1;
    int blk = (blockIdx.x < nblk) ? blockIdx.x : blockIdx.x - nblk;
    int bg = blk >> 4;                 // batches bg*4 .. bg*4+3
    int ic = blk & 15;                 // 32-col chunk
    int tid = threadIdx.x;
    int c = tid & 31, kh = tid >> 5;   // kh 0..15, each owns 32 k
    int i = ic * 32 + c;
    __shared__ float hs[4][512];
    __shared__ float ps[12][512];      // [gate*4+b][kh*32+c] (transposed: conflict-free)
    for (int j = tid; j < 2048; j += 512) {
        int bl = j >> 9, k = j & 511;
        hs[bl][k] = p.hb ? p.hb[(size_t)((bg * 4 + bl) * TT + p.tprev) * p.ystride + p.yoff + k]
                         : 0.f;
    }
    __syncthreads();
    float az[4] = {}, ar[4] = {}, ah[4] = {};
    const float* Up = p.U + (size_t)(kh * 32) * H3 + i;
    int ks0 = kh * 32;
#pragma unroll 8
    for (int k = 0; k < 32; ++k) {
        const float* Ur = Up + k * H3;
        float uz = Ur[0], ur = Ur[512], uh = Ur[1024];
#pragma unroll
        for (int b = 0; b < 4; ++b) {
            float h = hs[b][ks0 + k];                 // LDS broadcast within kh-group
            az[b] = fmaf(h, uz, az[b]);
            ar[b] = fmaf(h, ur, ar[b]);
            ah[b] = fmaf(h, uh, ah[b]);
        }
    }
#pragma unroll
    for (int b = 0; b < 4; ++b) {
        ps[b][tid] = az[b];
        ps[4 + b][tid] = ar[b];
        ps[8 + b][tid] = ah[b];
    }
    __syncthreads();
    if (tid < 128) {
        int b = tid >> 5, cc = tid & 31;
        float AZ = 0.f, AR = 0.f, AH = 0.f;
        for (int q = 0; q < 16; ++q) {
            AZ += ps[b][q * 32 + cc];
            AR += ps[4 + b][q * 32 + cc];
            AH += ps[8 + b][q * 32 + cc];
        }
        int ii = ic * 32 + cc;
        int row = (bg * 4 + b) * TT + p.t;
        const float* xr = p.xg + (size_t)row * H3;
        float z = sigm(xr[ii] + AZ + p.b1[ii]);
        float r = sigm(xr[512 + ii] + AR + p.b1[512 + ii]);
        float hc = sigm(xr[1024 + ii] + r * (AH + p.b1[1024 + ii]));
        float hp = hs[b][ii];
        float hn = (src[row] != 0) ? (z * hp + (1.f - z) * hc) : hp;
        p.y[(size_t)row * p.ystride + p.yoff + ii] = hn;
    }
}

// ---------------- decoder init: h0[b][i] = enc[b][T-1][i]
__global__ void k_copy_h0(const float* __restrict__ enc, float* __restrict__ h0) {
    int idx = blockIdx.x * 256 + threadIdx.x;
    int b = idx >> 9, i = idx & 511;
    h0[idx] = enc[((size_t)(b * TT + (TT - 1))) * HH + i];
}

// ---------------- fused q-GEMM + attention + context + xin (one block per b, 512 thr)
// q computed in-block (h @ aW2 + ab2); score/softmax/ctx shapes = proven R6/R7 bodies.
__global__ __launch_bounds__(512) void k_attn_q(
    const float* __restrict__ keys, const float* __restrict__ hbase,
    const float* __restrict__ aW2, const float* __restrict__ ab2,
    const float* __restrict__ aV, const float* __restrict__ abV,
    const float* __restrict__ enc, const float* __restrict__ emb_en,
    const int* __restrict__ trg, float* __restrict__ xin, int t) {
    int b = blockIdx.x;
    int tid = threadIdx.x;
    __shared__ float hsh[HH];
    __shared__ float qs[HH];
    __shared__ float sc[TT];
    hsh[tid] = hbase[b * HH + tid];
    __syncthreads();
    // q[tid] = ab2[tid] + sum_k h[k] * aW2[k][tid]  (coalesced: wave reads 64 consec cols)
    {
        float acc = 0.f;
        const float* Wp = aW2 + tid;
#pragma unroll 8
        for (int k = 0; k < HH; ++k) acc = fmaf(hsh[k], Wp[(size_t)k * HH], acc);
        qs[tid] = acc + ab2[tid];
    }
    __syncthreads();
    // scores: 4 threads per s over 128 h each (identical order to proven k_attn)
    if (tid < 256) {
        int s = tid >> 2, part = tid & 3;
        float p = 0.f;
        const float* kr = keys + (size_t)(b * TT + s) * HH;
        for (int h = part * 128; h < part * 128 + 128; ++h)
            p += tanhf(kr[h] + qs[h]) * aV[h];
        p += __shfl_down(p, 1);
        p += __shfl_down(p, 2);
        if (part == 0) sc[s] = p + abV[0];
    }
    __syncthreads();
    if (tid < 64) {
        float v = sc[tid];
        float m = v;
        for (int o = 1; o < 64; o <<= 1) m = fmaxf(m, __shfl_xor(m, o));
        float e = expf(v - m);
        float su = e;
        for (int o = 1; o < 64; o <<= 1) su += __shfl_xor(su, o);
        sc[tid] = e / su;
    }
    __syncthreads();
    // ctx: 512 threads, one h each (proven R6 order)
    {
        float cx = 0.f;
        for (int ss = 0; ss < TT; ++ss)
            cx += sc[ss] * enc[(size_t)(b * TT + ss) * HH + tid];
        xin[b * 768 + tid] = cx;
    }
    if (tid < 256) {
        int tok = (t == 0) ? 1 : trg[b * TT + t];
        xin[b * 768 + 512 + tid] = emb_en[tok * EE + tid];
    }
}

// ---------------- decoder GRU (h = 0), 4-batch-shared / 256-block / split-k-16 (R7-proven)
__global__ __launch_bounds__(512) void k_dec_gru5(
    const float* __restrict__ xin, const float* __restrict__ Wd,
    const float* __restrict__ bd, float* __restrict__ Hmat, int t) {
    int blk = blockIdx.x;
    int bg = blk >> 4;
    int ic = blk & 15;
    int tid = threadIdx.x;
    int c = tid & 31, kh = tid >> 5;
    int i = ic * 32 + c;
    __shared__ float xs[4][768];
    __shared__ float ps[12][512];
    for (int j = tid; j < 4 * 768; j += 512) {
        int bl = j / 768, k = j - bl * 768;
        xs[bl][k] = xin[(bg * 4 + bl) * 768 + k];
    }
    __syncthreads();
    float az[4] = {}, ar[4] = {}, ah[4] = {};
    const float* Wp = Wd + (size_t)(kh * 48) * H3 + i;
    int ks0 = kh * 48;
#pragma unroll 8
    for (int k = 0; k < 48; ++k) {
        const float* Wr = Wp + k * H3;
        float wz = Wr[0], wr = Wr[512], wh = Wr[1024];
#pragma unroll
        for (int b = 0; b < 4; ++b) {
            float x = xs[b][ks0 + k];
            az[b] = fmaf(x, wz, az[b]);
            ar[b] = fmaf(x, wr, ar[b]);
            ah[b] = fmaf(x, wh, ah[b]);
        }
    }
#pragma unroll
    for (int b = 0; b < 4; ++b) {
        ps[b][tid] = az[b];
        ps[4 + b][tid] = ar[b];
        ps[8 + b][tid] = ah[b];
    }
    __syncthreads();
    if (tid < 128) {
        int b = tid >> 5, cc = tid & 31;
        float AZ = 0.f, AR = 0.f, AH = 0.f;
        for (int q = 0; q < 16; ++q) {
            AZ += ps[b][q * 32 + cc];
            AR += ps[4 + b][q * 32 + cc];
            AH += ps[8 + b][q * 32 + cc];
        }
        int ii = ic * 32 + cc;
        const float* b0 = bd;
        const float* b1 = bd + H3;
        float z = sigm(AZ + b0[ii] + b1[ii]);
        float r = sigm(AR + b0[512 + ii] + b1[512 + ii]);
        float hc = sigm(AH + b0[1024 + ii] + r * b1[1024 + ii]);
        Hmat[((size_t)t * BB + bg * 4 + b) * HH + ii] = (1.f - z) * hc;
    }
}

// ---------------- logits GEMM (128x128, 8x8 micro) with fused online-LSE partials
__global__ __launch_bounds__(256) void k_gemm128_ce(
    const float* __restrict__ A, const float* __restrict__ W,
    const float* __restrict__ bias, const int* __restrict__ trg,
    float* __restrict__ pmax, float* __restrict__ psum, float* __restrict__ tgtl) {
    __shared__ float As[8][128];
    __shared__ float Bs[8][128];
    __shared__ float pm[128][17];
    __shared__ float ps[128][17];
    int row0 = blockIdx.y * 128, col0 = blockIdx.x * 128;
    int tid = threadIdx.x;
    int tx = tid & 15, ty = tid >> 4;
    int ar = tid >> 1, aq = tid & 1;
    int bkk = tid >> 5, bc4 = tid & 31;
    int arow = row0 + ar;
    if (arow > 4031) arow = 4031;   // clamp pad rows (reads stay in HMAT)
    float acc[2][2][4][4] = {};
    for (int k0 = 0; k0 < 512; k0 += 8) {
        float4 av = *(const float4*)&A[(size_t)arow * 512 + k0 + aq * 4];
        float4 bv = *(const float4*)&W[(size_t)(k0 + bkk) * VV + col0 + bc4 * 4];
        As[aq * 4 + 0][ar] = av.x;
        As[aq * 4 + 1][ar] = av.y;
        As[aq * 4 + 2][ar] = av.z;
        As[aq * 4 + 3][ar] = av.w;
        *(float4*)&Bs[bkk][bc4 * 4] = bv;
        __syncthreads();
#pragma unroll
        for (int kk = 0; kk < 8; ++kk) {
            float4 a0 = *(const float4*)&As[kk][ty * 4];
            float4 a1 = *(const float4*)&As[kk][64 + ty * 4];
            float4 b0 = *(const float4*)&Bs[kk][tx * 4];
            float4 b1 = *(const float4*)&Bs[kk][64 + tx * 4];
            float a_[2][4] = {{a0.x, a0.y, a0.z, a0.w}, {a1.x, a1.y, a1.z, a1.w}};
            float b_[2][4] = {{b0.x, b0.y, b0.z, b0.w}, {b1.x, b1.y, b1.z, b1.w}};
#pragma unroll
            for (int rh = 0; rh < 2; ++rh)
#pragma unroll
                for (int i = 0; i < 4; ++i)
#pragma unroll
                    for (int ch = 0; ch < 2; ++ch)
#pragma unroll
                        for (int j = 0; j < 4; ++j)
                            acc[rh][ch][i][j] = fmaf(a_[rh][i], b_[ch][j], acc[rh][ch][i][j]);
        }
        __syncthreads();
    }
#pragma unroll
    for (int rh = 0; rh < 2; ++rh)
#pragma unroll
        for (int i = 0; i < 4; ++i) {
            int rl = rh * 64 + ty * 4 + i;
            int rg = row0 + rl;
            int tdec = rg >> 6, bq = rg & 63;
            int tgt = (rg < 4032) ? trg[bq * TT + tdec + 1] : -1;
            float vv[8];
            float lm = -1e30f;
#pragma unroll
            for (int ch = 0; ch < 2; ++ch)
#pragma unroll
                for (int j = 0; j < 4; ++j) {
                    int c = col0 + ch * 64 + tx * 4 + j;
                    float v = acc[rh][ch][i][j] + bias[c];
                    vv[ch * 4 + j] = v;
                    lm = fmaxf(lm, v);
                    if (c == tgt) tgtl[rg] = v;
                }
            float ls = 0.f;
#pragma unroll
            for (int q = 0; q < 8; ++q) ls += expf(vv[q] - lm);
            pm[rl][tx] = lm;
            ps[rl][tx] = ls;
        }
    __syncthreads();
    if (tid < 128) {
        float M = -1e30f, S = 0.f;
        for (int x = 0; x < 16; ++x) {
            float m_ = pm[tid][x], s_ = ps[tid][x];
            if (m_ > M) { S = S * expf(M - m_) + s_; M = m_; }
            else        { S += s_ * expf(m_ - M); }
        }
        int rg = row0 + tid;
        if (rg < 4032) {
            pmax[(size_t)blockIdx.x * 4032 + rg] = M;
            psum[(size_t)blockIdx.x * 4032 + rg] = S;
        }
    }
}

// ---------------- merge partials per row -> per-block (ce_sum, valid_sum); coalesced
__global__ void k_merge(const float* __restrict__ pmax, const float* __restrict__ psum,
                        const float* __restrict__ tgtl, const int* __restrict__ trg,
                        float* __restrict__ blk) {
    int row = blockIdx.x * 64 + threadIdx.x;  // 4032 rows
    float M = -1e30f, S = 0.f;
    for (int c = 0; c < 250; ++c) {
        float m = pmax[(size_t)c * 4032 + row], s = psum[(size_t)c * 4032 + row];
        if (m > M) { S = S * expf(M - m) + s; M = m; }
        else       { S += s * expf(m - M); }
    }
    float lse = M + logf(S);
    int tdec = row >> 6, b = row & 63;
    int tgt = trg[b * TT + tdec + 1];
    float valid = (tgt != 0) ? 1.f : 0.f;
    float ce = (lse - tgtl[row]) * valid;
    float vs = valid;
    for (int o = 32; o > 0; o >>= 1) {
        ce += __shfl_down(ce, o);
        vs += __shfl_down(vs, o);
    }
    if (threadIdx.x == 0) {
        blk[blockIdx.x * 2] = ce;
        blk[blockIdx.x * 2 + 1] = vs;
    }
}

__global__ void k_final(const float* __restrict__ blk, float* __restrict__ out) {
    float s0 = 0.f, s1 = 0.f;
    for (int i = 0; i < 63; ++i) { s0 += blk[2 * i]; s1 += blk[2 * i + 1]; }
    out[0] = s0 / s1;
}

extern "C" void kernel_launch(void* const* d_in, const int* in_sizes, int n_in,
                              void* d_out, int out_size, void* d_ws, size_t ws_size,
                              hipStream_t stream) {
    const int* src = (const int*)d_in[0];
    const int* trg = (const int*)d_in[1];
    const float* emb_cn = (const float*)d_in[2];
    const float* Wf = (const float*)d_in[3];
    const float* Uf = (const float*)d_in[4];
    const float* bf = (const float*)d_in[5];
    const float* Wb = (const float*)d_in[6];
    const float* Ub = (const float*)d_in[7];
    const float* bb = (const float*)d_in[8];
    const float* Wm = (const float*)d_in[9];
    const float* Um = (const float*)d_in[10];
    const float* bm = (const float*)d_in[11];
    const float* Wt = (const float*)d_in[12];
    const float* Ut = (const float*)d_in[13];
    const float* bt = (const float*)d_in[14];
    const float* emb_en = (const float*)d_in[15];
    const float* aW1 = (const float*)d_in[16];
    const float* ab1 = (const float*)d_in[17];
    const float* aW2 = (const float*)d_in[18];
    const float* ab2 = (const float*)d_in[19];
    const float* aV = (const float*)d_in[20];
    const float* abV = (const float*)d_in[21];
    const float* Wd = (const float*)d_in[22];
    const float* bd = (const float*)d_in[24];
    const float* fcW = (const float*)d_in[25];
    const float* fcb = (const float*)d_in[26];
    float* ws = (float*)d_ws;
    float* out = (float*)d_out;

    // workspace layout (floats); PMAX/PSUM alias the x_emb/XG region (dead by then)
    float* X_EMB = ws;                    // 1,048,576
    float* XG    = ws + 1048576;          // 6,291,456
    float* PMAX  = ws;                    // 1,008,000 (alias, 250 x 4032)
    float* PSUM  = ws + 1008000;          // 1,008,000 (alias)
    float* X2    = ws + 7340032;          // 4,194,304
    float* XGB   = ws + 11534336;         // 6,291,456 (aliases Y3/ENC/KEYS, dead during f||b)
    float* Y3    = ws + 11534336;         // 2,097,152
    float* ENC   = ws + 13631488;         // 2,097,152
    float* KEYS  = ws + 15728640;         // 2,097,152
    float* HMAT  = ws + 17825792;         // 2,064,384
    float* H0v   = ws + 19890176;         // 32,768
    float* XIN   = ws + 19955712;         // 49,152
    float* TGTL  = ws + 20004864;         // 4,032
    float* BLK   = ws + 20008896;         // 126

    k_embed<<<4096, 256, 0, stream>>>(src, emb_cn, X_EMB);

    // x-gates for f and b (independent), then run both layers in lockstep
    k_gemm128_bias<<<dim3(12, 32), 256, 0, stream>>>(X_EMB, Wf, bf, XG, 1536, 256);
    k_gemm128_bias<<<dim3(12, 32), 256, 0, stream>>>(X_EMB, Wb, bb, XGB, 1536, 256);
    for (int s = 0; s < 64; ++s) {
        GruP pf{XG, s ? X2 : nullptr, X2, Uf, bf + H3, s, s - 1, 1024, 0};
        GruP pb{XGB, s ? X2 : nullptr, X2, Ub, bb + H3, 63 - s, 64 - s, 1024, 512};
        k_gru5<<<512, 512, 0, stream>>>(pf, pb, src, 256);
    }
    // layer m
    k_gemm128_bias<<<dim3(12, 32), 256, 0, stream>>>(X2, Wm, bm, XG, 1536, 1024);
    for (int t = 0; t < 64; ++t) {
        GruP pm_{XG, t ? Y3 : nullptr, Y3, Um, bm + H3, t, t - 1, 512, 0};
        k_gru5<<<256, 512, 0, stream>>>(pm_, pm_, src, 256);
    }
    // layer t
    k_gemm128_bias<<<dim3(12, 32), 256, 0, stream>>>(Y3, Wt, bt, XG, 1536, 512);
    for (int t = 0; t < 64; ++t) {
        GruP pt_{XG, t ? ENC : nullptr, ENC, Ut, bt + H3, t, t - 1, 512, 0};
        k_gru5<<<256, 512, 0, stream>>>(pt_, pt_, src, 256);
    }
    // keys + decoder init
    k_gemm128_bias<<<dim3(4, 32), 256, 0, stream>>>(ENC, aW1, ab1, KEYS, 512, 512);
    k_copy_h0<<<128, 256, 0, stream>>>(ENC, H0v);

    // decoder: 63 sequential steps x 2 kernels (q fused into attention)
    for (int t = 0; t < TDEC; ++t) {
        const float* hq = (t == 0) ? H0v : (HMAT + (size_t)(t - 1) * 32768);
        k_attn_q<<<64, 512, 0, stream>>>(KEYS, hq, aW2, ab2, aV, abV, ENC, emb_en, trg, XIN, t);
        k_dec_gru5<<<256, 512, 0, stream>>>(XIN, Wd, bd, HMAT, t);
    }

    // batched logits + CE
    k_gemm128_ce<<<dim3(250, 32), 256, 0, stream>>>(HMAT, fcW, fcb, trg, PMAX, PSUM, TGTL);
    k_merge<<<63, 64, 0, stream>>>(PMAX, PSUM, TGTL, trg, BLK);
    k_final<<<1, 1, 0, stream>>>(BLK, out);
}

// Round 10
// 7282.693 us; speedup vs baseline: 5.8682x; 1.0298x over previous
//
#include <hip/hip_runtime.h>
#include <math.h>

#define HH 512
#define EE 256
#define BB 64
#define TT 64
#define VV 32000
#define H3 1536
#define TDEC 63

__device__ __forceinline__ float sigm(float x) { return 1.f / (1.f + expf(-x)); }

// ---------------- embedding gather: x[b*T+t][e] = emb[src[b*T+t]][e]
__global__ void k_embed(const int* __restrict__ src, const float* __restrict__ emb,
                        float* __restrict__ x) {
    int idx = blockIdx.x * 256 + threadIdx.x;      // B*T*E = 1048576
    int row = idx >> 8;
    int e = idx & 255;
    x[idx] = emb[src[row] * EE + e];
}

// ---------------- 128x128 fp32 GEMM + bias, 8x8 micro-tile (split 64+64), R5-proven
__global__ __launch_bounds__(256) void k_gemm128_bias(
    const float* __restrict__ A, const float* __restrict__ W,
    const float* __restrict__ bias, float* __restrict__ C,
    int N, int K) {
    __shared__ float As[8][128];
    __shared__ float Bs[8][128];
    int row0 = blockIdx.y * 128, col0 = blockIdx.x * 128;
    int tid = threadIdx.x;
    int tx = tid & 15, ty = tid >> 4;
    int ar = tid >> 1, aq = tid & 1;
    int bkk = tid >> 5, bc4 = tid & 31;
    float acc[2][2][4][4] = {};
    for (int k0 = 0; k0 < K; k0 += 8) {
        float4 av = *(const float4*)&A[(size_t)(row0 + ar) * K + k0 + aq * 4];
        float4 bv = *(const float4*)&W[(size_t)(k0 + bkk) * N + col0 + bc4 * 4];
        As[aq * 4 + 0][ar] = av.x;
        As[aq * 4 + 1][ar] = av.y;
        As[aq * 4 + 2][ar] = av.z;
        As[aq * 4 + 3][ar] = av.w;
        *(float4*)&Bs[bkk][bc4 * 4] = bv;
        __syncthreads();
#pragma unroll
        for (int kk = 0; kk < 8; ++kk) {
            float4 a0 = *(const float4*)&As[kk][ty * 4];
            float4 a1 = *(const float4*)&As[kk][64 + ty * 4];
            float4 b0 = *(const float4*)&Bs[kk][tx * 4];
            float4 b1 = *(const float4*)&Bs[kk][64 + tx * 4];
            float a_[2][4] = {{a0.x, a0.y, a0.z, a0.w}, {a1.x, a1.y, a1.z, a1.w}};
            float b_[2][4] = {{b0.x, b0.y, b0.z, b0.w}, {b1.x, b1.y, b1.z, b1.w}};
#pragma unroll
            for (int rh = 0; rh < 2; ++rh)
#pragma unroll
                for (int i = 0; i < 4; ++i)
#pragma unroll
                    for (int ch = 0; ch < 2; ++ch)
#pragma unroll
                        for (int j = 0; j < 4; ++j)
                            acc[rh][ch][i][j] = fmaf(a_[rh][i], b_[ch][j], acc[rh][ch][i][j]);
        }
        __syncthreads();
    }
#pragma unroll
    for (int rh = 0; rh < 2; ++rh)
#pragma unroll
        for (int i = 0; i < 4; ++i) {
            int row = row0 + rh * 64 + ty * 4 + i;
#pragma unroll
            for (int ch = 0; ch < 2; ++ch) {
                int c = col0 + ch * 64 + tx * 4;
                float4 bv = *(const float4*)&bias[c];
                float4 o;
                o.x = acc[rh][ch][i][0] + bv.x;
                o.y = acc[rh][ch][i][1] + bv.y;
                o.z = acc[rh][ch][i][2] + bv.z;
                o.w = acc[rh][ch][i][3] + bv.w;
                *(float4*)&C[(size_t)row * N + c] = o;
            }
        }
}

// ---------------- GRU recurrent step, 4-batch-shared / 256-block / split-k-16 (R7-proven)
struct GruP {
    const float* xg;     // (B*T, 3H)
    const float* hb;     // carried h base (nullptr -> zeros)
    float* y;
    const float* U;      // (H, 3H)
    const float* b1;     // (3H)
    int t, tprev, ystride, yoff;
};

__global__ __launch_bounds__(512) void k_gru5(GruP p0, GruP p1, const int* __restrict__ src,
                                              int nblk) {
    GruP p = (blockIdx.x < nblk) ? p0 : p1;
    int blk = (blockIdx.x < nblk) ? blockIdx.x : blockIdx.x - nblk;
    int bg = blk >> 4;                 // batches bg*4 .. bg*4+3
    int ic = blk & 15;                 // 32-col chunk
    int tid = threadIdx.x;
    int c = tid & 31, kh = tid >> 5;   // kh 0..15, each owns 32 k
    int i = ic * 32 + c;
    __shared__ float hs[4][512];
    __shared__ float ps[12][512];      // [gate*4+b][kh*32+c] (transposed: conflict-free)
    for (int j = tid; j < 2048; j += 512) {
        int bl = j >> 9, k = j & 511;
        hs[bl][k] = p.hb ? p.hb[(size_t)((bg * 4 + bl) * TT + p.tprev) * p.ystride + p.yoff + k]
                         : 0.f;
    }
    __syncthreads();
    float az[4] = {}, ar[4] = {}, ah[4] = {};
    const float* Up = p.U + (size_t)(kh * 32) * H3 + i;
    int ks0 = kh * 32;
#pragma unroll 8
    for (int k = 0; k < 32; ++k) {
        const float* Ur = Up + k * H3;
        float uz = Ur[0], ur = Ur[512], uh = Ur[1024];
#pragma unroll
        for (int b = 0; b < 4; ++b) {
            float h = hs[b][ks0 + k];                 // LDS broadcast within kh-group
            az[b] = fmaf(h, uz, az[b]);
            ar[b] = fmaf(h, ur, ar[b]);
            ah[b] = fmaf(h, uh, ah[b]);
        }
    }
#pragma unroll
    for (int b = 0; b < 4; ++b) {
        ps[b][tid] = az[b];
        ps[4 + b][tid] = ar[b];
        ps[8 + b][tid] = ah[b];
    }
    __syncthreads();
    if (tid < 128) {
        int b = tid >> 5, cc = tid & 31;
        float AZ = 0.f, AR = 0.f, AH = 0.f;
        for (int q = 0; q < 16; ++q) {
            AZ += ps[b][q * 32 + cc];
            AR += ps[4 + b][q * 32 + cc];
            AH += ps[8 + b][q * 32 + cc];
        }
        int ii = ic * 32 + cc;
        int row = (bg * 4 + b) * TT + p.t;
        const float* xr = p.xg + (size_t)row * H3;
        float z = sigm(xr[ii] + AZ + p.b1[ii]);
        float r = sigm(xr[512 + ii] + AR + p.b1[512 + ii]);
        float hc = sigm(xr[1024 + ii] + r * (AH + p.b1[1024 + ii]));
        float hp = hs[b][ii];
        float hn = (src[row] != 0) ? (z * hp + (1.f - z) * hc) : hp;
        p.y[(size_t)row * p.ystride + p.yoff + ii] = hn;
    }
}

// ---------------- pipelined encoder step: m-phase (xg precomputed) || t-phase (xg fused)
// 512 blocks: 0..255 = m[s] (k_gru5 body), 256..511 = t[s-1] with on-the-fly x@Wt matvec.
struct EncP {
    const float* xg;     // m-phase: precomputed gates; t-phase: nullptr (fused)
    const float* xseq;   // t-phase: input sequence (B*T, 512)
    const float* xW;     // t-phase: W (512, 3H)
    const float* xb0;    // t-phase: x-bias (row 0 of b)
    float* y;            // output sequence
    const float* U;      // (H, 3H)
    const float* b1;     // recurrent bias (row 1)
    int t;               // timestep this stage (-1 = inactive)
    int ystride, yoff;
};

__global__ __launch_bounds__(512) void k_enc_step(EncP pm, EncP pt, const int* __restrict__ src) {
    EncP p = (blockIdx.x < 256) ? pm : pt;
    if (p.t < 0) return;
    int blk = blockIdx.x & 255;
    int bg = blk >> 4, ic = blk & 15;
    int tid = threadIdx.x;
    int c = tid & 31, kh = tid >> 5;
    int i = ic * 32 + c;
    __shared__ float hs[4][512];
    __shared__ float xs[4][512];
    __shared__ float ps[16][512];
    bool fused = (p.xg == nullptr);
    int tprev = p.t - 1;
    for (int j = tid; j < 2048; j += 512) {
        int bl = j >> 9, k = j & 511;
        hs[bl][k] = (tprev < 0) ? 0.f
            : p.y[(size_t)((bg * 4 + bl) * TT + tprev) * p.ystride + p.yoff + k];
        if (fused)
            xs[bl][k] = p.xseq[(size_t)((bg * 4 + bl) * TT + p.t) * 512 + k];
    }
    __syncthreads();
    float az[4] = {}, ar[4] = {}, ahU[4] = {}, ahW[4] = {};
    int ks0 = kh * 32;
    {
        const float* Up = p.U + (size_t)ks0 * H3 + i;
#pragma unroll 8
        for (int k = 0; k < 32; ++k) {
            const float* Ur = Up + k * H3;
            float uz = Ur[0], ur = Ur[512], uh = Ur[1024];
#pragma unroll
            for (int b = 0; b < 4; ++b) {
                float h = hs[b][ks0 + k];
                az[b] = fmaf(h, uz, az[b]);
                ar[b] = fmaf(h, ur, ar[b]);
                ahU[b] = fmaf(h, uh, ahU[b]);
            }
        }
    }
    if (fused) {
        const float* Wp = p.xW + (size_t)ks0 * H3 + i;
#pragma unroll 8
        for (int k = 0; k < 32; ++k) {
            const float* Wr = Wp + k * H3;
            float wz = Wr[0], wr = Wr[512], wh = Wr[1024];
#pragma unroll
            for (int b = 0; b < 4; ++b) {
                float x = xs[b][ks0 + k];
                az[b] = fmaf(x, wz, az[b]);
                ar[b] = fmaf(x, wr, ar[b]);
                ahW[b] = fmaf(x, wh, ahW[b]);
            }
        }
    }
#pragma unroll
    for (int b = 0; b < 4; ++b) {
        ps[b][tid] = az[b];
        ps[4 + b][tid] = ar[b];
        ps[8 + b][tid] = ahU[b];
        ps[12 + b][tid] = ahW[b];
    }
    __syncthreads();
    if (tid < 128) {
        int b = tid >> 5, cc = tid & 31;
        float AZ = 0.f, AR = 0.f, AHU = 0.f, AHW = 0.f;
        for (int q = 0; q < 16; ++q) {
            AZ += ps[b][q * 32 + cc];
            AR += ps[4 + b][q * 32 + cc];
            AHU += ps[8 + b][q * 32 + cc];
            AHW += ps[12 + b][q * 32 + cc];
        }
        int ii = ic * 32 + cc;
        int row = (bg * 4 + b) * TT + p.t;
        float xz, xr_, xh;
        if (fused) {
            xz = p.xb0[ii];
            xr_ = p.xb0[512 + ii];
            xh = AHW + p.xb0[1024 + ii];
        } else {
            const float* xr = p.xg + (size_t)row * H3;
            xz = xr[ii];
            xr_ = xr[512 + ii];
            xh = xr[1024 + ii];
        }
        float z = sigm(xz + AZ + p.b1[ii]);
        float r = sigm(xr_ + AR + p.b1[512 + ii]);
        float hc = sigm(xh + r * (AHU + p.b1[1024 + ii]));
        float hp = hs[b][ii];
        float hn = (src[row] != 0) ? (z * hp + (1.f - z) * hc) : hp;
        p.y[(size_t)row * p.ystride + p.yoff + ii] = hn;
    }
}

// ---------------- decoder init: h0[b][i] = enc[b][T-1][i]
__global__ void k_copy_h0(const float* __restrict__ enc, float* __restrict__ h0) {
    int idx = blockIdx.x * 256 + threadIdx.x;
    int b = idx >> 9, i = idx & 511;
    h0[idx] = enc[((size_t)(b * TT + (TT - 1))) * HH + i];
}

// ---------------- fused q-GEMM + attention + context + xin (one block per b, 512 thr)
__global__ __launch_bounds__(512) void k_attn_q(
    const float* __restrict__ keys, const float* __restrict__ hbase,
    const float* __restrict__ aW2, const float* __restrict__ ab2,
    const float* __restrict__ aV, const float* __restrict__ abV,
    const float* __restrict__ enc, const float* __restrict__ emb_en,
    const int* __restrict__ trg, float* __restrict__ xin, int t) {
    int b = blockIdx.x;
    int tid = threadIdx.x;
    __shared__ float hsh[HH];
    __shared__ float qs[HH];
    __shared__ float sc[TT];
    hsh[tid] = hbase[b * HH + tid];
    __syncthreads();
    // q[tid] = ab2[tid] + sum_k h[k] * aW2[k][tid]  (coalesced: wave reads 64 consec cols)
    {
        float acc = 0.f;
        const float* Wp = aW2 + tid;
#pragma unroll 8
        for (int k = 0; k < HH; ++k) acc = fmaf(hsh[k], Wp[(size_t)k * HH], acc);
        qs[tid] = acc + ab2[tid];
    }
    __syncthreads();
    // scores: 4 threads per s over 128 h each (identical order to proven k_attn)
    if (tid < 256) {
        int s = tid >> 2, part = tid & 3;
        float p = 0.f;
        const float* kr = keys + (size_t)(b * TT + s) * HH;
        for (int h = part * 128; h < part * 128 + 128; ++h)
            p += tanhf(kr[h] + qs[h]) * aV[h];
        p += __shfl_down(p, 1);
        p += __shfl_down(p, 2);
        if (part == 0) sc[s] = p + abV[0];
    }
    __syncthreads();
    if (tid < 64) {
        float v = sc[tid];
        float m = v;
        for (int o = 1; o < 64; o <<= 1) m = fmaxf(m, __shfl_xor(m, o));
        float e = expf(v - m);
        float su = e;
        for (int o = 1; o < 64; o <<= 1) su += __shfl_xor(su, o);
        sc[tid] = e / su;
    }
    __syncthreads();
    // ctx: 512 threads, one h each (proven R6 order)
    {
        float cx = 0.f;
        for (int ss = 0; ss < TT; ++ss)
            cx += sc[ss] * enc[(size_t)(b * TT + ss) * HH + tid];
        xin[b * 768 + tid] = cx;
    }
    if (tid < 256) {
        int tok = (t == 0) ? 1 : trg[b * TT + t];
        xin[b * 768 + 512 + tid] = emb_en[tok * EE + tid];
    }
}

// ---------------- decoder GRU (h = 0), 4-batch-shared / 256-block / split-k-16 (R7-proven)
__global__ __launch_bounds__(512) void k_dec_gru5(
    const float* __restrict__ xin, const float* __restrict__ Wd,
    const float* __restrict__ bd, float* __restrict__ Hmat, int t) {
    int blk = blockIdx.x;
    int bg = blk >> 4;
    int ic = blk & 15;
    int tid = threadIdx.x;
    int c = tid & 31, kh = tid >> 5;
    int i = ic * 32 + c;
    __shared__ float xs[4][768];
    __shared__ float ps[12][512];
    for (int j = tid; j < 4 * 768; j += 512) {
        int bl = j / 768, k = j - bl * 768;
        xs[bl][k] = xin[(bg * 4 + bl) * 768 + k];
    }
    __syncthreads();
    float az[4] = {}, ar[4] = {}, ah[4] = {};
    const float* Wp = Wd + (size_t)(kh * 48) * H3 + i;
    int ks0 = kh * 48;
#pragma unroll 8
    for (int k = 0; k < 48; ++k) {
        const float* Wr = Wp + k * H3;
        float wz = Wr[0], wr = Wr[512], wh = Wr[1024];
#pragma unroll
        for (int b = 0; b < 4; ++b) {
            float x = xs[b][ks0 + k];
            az[b] = fmaf(x, wz, az[b]);
            ar[b] = fmaf(x, wr, ar[b]);
            ah[b] = fmaf(x, wh, ah[b]);
        }
    }
#pragma unroll
    for (int b = 0; b < 4; ++b) {
        ps[b][tid] = az[b];
        ps[4 + b][tid] = ar[b];
        ps[8 + b][tid] = ah[b];
    }
    __syncthreads();
    if (tid < 128) {
        int b = tid >> 5, cc = tid & 31;
        float AZ = 0.f, AR = 0.f, AH = 0.f;
        for (int q = 0; q < 16; ++q) {
            AZ += ps[b][q * 32 + cc];
            AR += ps[4 + b][q * 32 + cc];
            AH += ps[8 + b][q * 32 + cc];
        }
        int ii = ic * 32 + cc;
        const float* b0 = bd;
        const float* b1 = bd + H3;
        float z = sigm(AZ + b0[ii] + b1[ii]);
        float r = sigm(AR + b0[512 + ii] + b1[512 + ii]);
        float hc = sigm(AH + b0[1024 + ii] + r * b1[1024 + ii]);
        Hmat[((size_t)t * BB + bg * 4 + b) * HH + ii] = (1.f - z) * hc;
    }
}

// ---------------- logits GEMM (128x128, 8x8 micro) with fused online-LSE partials
__global__ __launch_bounds__(256) void k_gemm128_ce(
    const float* __restrict__ A, const float* __restrict__ W,
    const float* __restrict__ bias, const int* __restrict__ trg,
    float* __restrict__ pmax, float* __restrict__ psum, float* __restrict__ tgtl) {
    __shared__ float As[8][128];
    __shared__ float Bs[8][128];
    __shared__ float pm[128][17];
    __shared__ float ps[128][17];
    int row0 = blockIdx.y * 128, col0 = blockIdx.x * 128;
    int tid = threadIdx.x;
    int tx = tid & 15, ty = tid >> 4;
    int ar = tid >> 1, aq = tid & 1;
    int bkk = tid >> 5, bc4 = tid & 31;
    int arow = row0 + ar;
    if (arow > 4031) arow = 4031;   // clamp pad rows (reads stay in HMAT)
    float acc[2][2][4][4] = {};
    for (int k0 = 0; k0 < 512; k0 += 8) {
        float4 av = *(const float4*)&A[(size_t)arow * 512 + k0 + aq * 4];
        float4 bv = *(const float4*)&W[(size_t)(k0 + bkk) * VV + col0 + bc4 * 4];
        As[aq * 4 + 0][ar] = av.x;
        As[aq * 4 + 1][ar] = av.y;
        As[aq * 4 + 2][ar] = av.z;
        As[aq * 4 + 3][ar] = av.w;
        *(float4*)&Bs[bkk][bc4 * 4] = bv;
        __syncthreads();
#pragma unroll
        for (int kk = 0; kk < 8; ++kk) {
            float4 a0 = *(const float4*)&As[kk][ty * 4];
            float4 a1 = *(const float4*)&As[kk][64 + ty * 4];
            float4 b0 = *(const float4*)&Bs[kk][tx * 4];
            float4 b1 = *(const float4*)&Bs[kk][64 + tx * 4];
            float a_[2][4] = {{a0.x, a0.y, a0.z, a0.w}, {a1.x, a1.y, a1.z, a1.w}};
            float b_[2][4] = {{b0.x, b0.y, b0.z, b0.w}, {b1.x, b1.y, b1.z, b1.w}};
#pragma unroll
            for (int rh = 0; rh < 2; ++rh)
#pragma unroll
                for (int i = 0; i < 4; ++i)
#pragma unroll
                    for (int ch = 0; ch < 2; ++ch)
#pragma unroll
                        for (int j = 0; j < 4; ++j)
                            acc[rh][ch][i][j] = fmaf(a_[rh][i], b_[ch][j], acc[rh][ch][i][j]);
        }
        __syncthreads();
    }
#pragma unroll
    for (int rh = 0; rh < 2; ++rh)
#pragma unroll
        for (int i = 0; i < 4; ++i) {
            int rl = rh * 64 + ty * 4 + i;
            int rg = row0 + rl;
            int tdec = rg >> 6, bq = rg & 63;
            int tgt = (rg < 4032) ? trg[bq * TT + tdec + 1] : -1;
            float vv[8];
            float lm = -1e30f;
#pragma unroll
            for (int ch = 0; ch < 2; ++ch)
#pragma unroll
                for (int j = 0; j < 4; ++j) {
                    int c = col0 + ch * 64 + tx * 4 + j;
                    float v = acc[rh][ch][i][j] + bias[c];
                    vv[ch * 4 + j] = v;
                    lm = fmaxf(lm, v);
                    if (c == tgt) tgtl[rg] = v;
                }
            float ls = 0.f;
#pragma unroll
            for (int q = 0; q < 8; ++q) ls += expf(vv[q] - lm);
            pm[rl][tx] = lm;
            ps[rl][tx] = ls;
        }
    __syncthreads();
    if (tid < 128) {
        float M = -1e30f, S = 0.f;
        for (int x = 0; x < 16; ++x) {
            float m_ = pm[tid][x], s_ = ps[tid][x];
            if (m_ > M) { S = S * expf(M - m_) + s_; M = m_; }
            else        { S += s_ * expf(m_ - M); }
        }
        int rg = row0 + tid;
        if (rg < 4032) {
            pmax[(size_t)blockIdx.x * 4032 + rg] = M;
            psum[(size_t)blockIdx.x * 4032 + rg] = S;
        }
    }
}

// ---------------- merge partials per row -> per-block (ce_sum, valid_sum); coalesced
__global__ void k_merge(const float* __restrict__ pmax, const float* __restrict__ psum,
                        const float* __restrict__ tgtl, const int* __restrict__ trg,
                        float* __restrict__ blk) {
    int row = blockIdx.x * 64 + threadIdx.x;  // 4032 rows
    float M = -1e30f, S = 0.f;
    for (int c = 0; c < 250; ++c) {
        float m = pmax[(size_t)c * 4032 + row], s = psum[(size_t)c * 4032 + row];
        if (m > M) { S = S * expf(M - m) + s; M = m; }
        else       { S += s * expf(m - M); }
    }
    float lse = M + logf(S);
    int tdec = row >> 6, b = row & 63;
    int tgt = trg[b * TT + tdec + 1];
    float valid = (tgt != 0) ? 1.f : 0.f;
    float ce = (lse - tgtl[row]) * valid;
    float vs = valid;
    for (int o = 32; o > 0; o >>= 1) {
        ce += __shfl_down(ce, o);
        vs += __shfl_down(vs, o);
    }
    if (threadIdx.x == 0) {
        blk[blockIdx.x * 2] = ce;
        blk[blockIdx.x * 2 + 1] = vs;
    }
}

__global__ void k_final(const float* __restrict__ blk, float* __restrict__ out) {
    float s0 = 0.f, s1 = 0.f;
    for (int i = 0; i < 63; ++i) { s0 += blk[2 * i]; s1 += blk[2 * i + 1]; }
    out[0] = s0 / s1;
}

extern "C" void kernel_launch(void* const* d_in, const int* in_sizes, int n_in,
                              void* d_out, int out_size, void* d_ws, size_t ws_size,
                              hipStream_t stream) {
    const int* src = (const int*)d_in[0];
    const int* trg = (const int*)d_in[1];
    const float* emb_cn = (const float*)d_in[2];
    const float* Wf = (const float*)d_in[3];
    const float* Uf = (const float*)d_in[4];
    const float* bf = (const float*)d_in[5];
    const float* Wb = (const float*)d_in[6];
    const float* Ub = (const float*)d_in[7];
    const float* bb = (const float*)d_in[8];
    const float* Wm = (const float*)d_in[9];
    const float* Um = (const float*)d_in[10];
    const float* bm = (const float*)d_in[11];
    const float* Wt = (const float*)d_in[12];
    const float* Ut = (const float*)d_in[13];
    const float* bt = (const float*)d_in[14];
    const float* emb_en = (const float*)d_in[15];
    const float* aW1 = (const float*)d_in[16];
    const float* ab1 = (const float*)d_in[17];
    const float* aW2 = (const float*)d_in[18];
    const float* ab2 = (const float*)d_in[19];
    const float* aV = (const float*)d_in[20];
    const float* abV = (const float*)d_in[21];
    const float* Wd = (const float*)d_in[22];
    const float* bd = (const float*)d_in[24];
    const float* fcW = (const float*)d_in[25];
    const float* fcb = (const float*)d_in[26];
    float* ws = (float*)d_ws;
    float* out = (float*)d_out;

    // workspace layout (floats); PMAX/PSUM alias the x_emb/XG region (dead by then)
    float* X_EMB = ws;                    // 1,048,576
    float* XG    = ws + 1048576;          // 6,291,456
    float* PMAX  = ws;                    // 1,008,000 (alias, 250 x 4032)
    float* PSUM  = ws + 1008000;          // 1,008,000 (alias)
    float* X2    = ws + 7340032;          // 4,194,304
    float* XGB   = ws + 11534336;         // 6,291,456 (aliases Y3/ENC/KEYS, dead during f||b)
    float* Y3    = ws + 11534336;         // 2,097,152
    float* ENC   = ws + 13631488;         // 2,097,152
    float* KEYS  = ws + 15728640;         // 2,097,152
    float* HMAT  = ws + 17825792;         // 2,064,384
    float* H0v   = ws + 19890176;         // 32,768
    float* XIN   = ws + 19955712;         // 49,152
    float* TGTL  = ws + 20004864;         // 4,032
    float* BLK   = ws + 20008896;         // 126

    k_embed<<<4096, 256, 0, stream>>>(src, emb_cn, X_EMB);

    // x-gates for f and b (independent), then run both layers in lockstep
    k_gemm128_bias<<<dim3(12, 32), 256, 0, stream>>>(X_EMB, Wf, bf, XG, 1536, 256);
    k_gemm128_bias<<<dim3(12, 32), 256, 0, stream>>>(X_EMB, Wb, bb, XGB, 1536, 256);
    for (int s = 0; s < 64; ++s) {
        GruP pf{XG, s ? X2 : nullptr, X2, Uf, bf + H3, s, s - 1, 1024, 0};
        GruP pb{XGB, s ? X2 : nullptr, X2, Ub, bb + H3, 63 - s, 64 - s, 1024, 512};
        k_gru5<<<512, 512, 0, stream>>>(pf, pb, src, 256);
    }
    // layer m x-gates, then pipelined m || t wavefront (t-layer xg fused on the fly)
    k_gemm128_bias<<<dim3(12, 32), 256, 0, stream>>>(X2, Wm, bm, XG, 1536, 1024);
    for (int s = 0; s <= 64; ++s) {
        EncP pm_{XG, nullptr, nullptr, nullptr, Y3, Um, bm + H3,
                 (s <= 63) ? s : -1, 512, 0};
        EncP pt_{nullptr, Y3, Wt, bt, ENC, Ut, bt + H3,
                 s - 1, 512, 0};
        k_enc_step<<<512, 512, 0, stream>>>(pm_, pt_, src);
    }
    // keys + decoder init
    k_gemm128_bias<<<dim3(4, 32), 256, 0, stream>>>(ENC, aW1, ab1, KEYS, 512, 512);
    k_copy_h0<<<128, 256, 0, stream>>>(ENC, H0v);

    // decoder: 63 sequential steps x 2 kernels (q fused into attention)
    for (int t = 0; t < TDEC; ++t) {
        const float* hq = (t == 0) ? H0v : (HMAT + (size_t)(t - 1) * 32768);
        k_attn_q<<<64, 512, 0, stream>>>(KEYS, hq, aW2, ab2, aV, abV, ENC, emb_en, trg, XIN, t);
        k_dec_gru5<<<256, 512, 0, stream>>>(XIN, Wd, bd, HMAT, t);
    }

    // batched logits + CE
    k_gemm128_ce<<<dim3(250, 32), 256, 0, stream>>>(HMAT, fcW, fcb, trg, PMAX, PSUM, TGTL);
    k_merge<<<63, 64, 0, stream>>>(PMAX, PSUM, TGTL, trg, BLK);
    k_final<<<1, 1, 0, stream>>>(BLK, out);
}